// Round 4
// baseline (1787.432 us; speedup 1.0000x reference)
//
#include <hip/hip_runtime.h>

#define GRP 8
#define SUBD 64
#define NCODE 1024
#define TLEN 4096
#define NBATCH 8
#define NVEC (NBATCH * TLEN)          // 32768
#define QOUT (NBATCH * 512 * TLEN)    // 16777216
#define NGRPS (NCODE / 8)             // 128 groups of 8 codes

// ws layout (bytes), all 64-B aligned:
// [0]       double lossAcc[2]
// [64]      float e2[2*GRP*NCODE]              64 KB   ([cb][g][k], 32-B alignable)
// [65600]   int   idx1[GRP*NVEC]               1 MB
// [1114176] float cbP1[GRP*NGRPS*SUBD*8]       2 MB    panel: [g][grp][d][8k]
// [3211328] float cbP2[...]                    2 MB
#define WS_E2 64
#define WS_IDX1 (WS_E2 + 65536)
#define WS_P1 (WS_IDX1 + 1048576)
#define WS_P2 (WS_P1 + 2097152)

typedef float f8 __attribute__((ext_vector_type(8)));

__global__ __launch_bounds__(256) void k_e2(const float* __restrict__ cb1,
                                            const float* __restrict__ cb2,
                                            float* __restrict__ e2) {
    int i = blockIdx.x * 256 + threadIdx.x;      // 0 .. 16383
    const float* c = (i < GRP * NCODE) ? (cb1 + (size_t)i * SUBD)
                                       : (cb2 + (size_t)(i - GRP * NCODE) * SUBD);
    float s = 0.f;
#pragma unroll
    for (int d = 0; d < SUBD; ++d) s = __builtin_fmaf(c[d], c[d], s);
    e2[i] = s;
}

// Panel repack: cbP[g][grp][d][j] = cb[g][grp*8+j][d]. One thread per code row.
__global__ __launch_bounds__(256) void k_panel(const float* __restrict__ cb1,
                                               const float* __restrict__ cb2,
                                               float* __restrict__ cbP1,
                                               float* __restrict__ cbP2) {
    int i = blockIdx.x * 256 + threadIdx.x;      // 0 .. 16383
    int sel = i >> 13, rest = i & 8191, g = rest >> 10, k = rest & 1023;
    int grp = k >> 3, j = k & 7;
    const float* src = (sel ? cb2 : cb1) + ((size_t)g * NCODE + k) * SUBD;
    float* dst = (sel ? cbP2 : cbP1) + ((size_t)(g * NGRPS + grp) * SUBD) * 8 + j;
#pragma unroll
    for (int s = 0; s < 16; ++s) {
        float4 v = ((const float4*)src)[s];
#pragma unroll
        for (int dd = 0; dd < 4; ++dd) dst[(4 * s + dd) * 8] = ((const float*)&v)[dd];
    }
}

// Stage 1: lane = one (row n, group g). r[64] in VGPRs; codes wave-uniform from
// panel (s_load path; fallback global with imm offsets). Each acc is one
// ascending-d fma chain; dist = fma(-2, acc, fl(x2+e2)); ascending-k strict <.
__global__ __launch_bounds__(256, 4) void k_vq1(const float* __restrict__ x,
                                                const float* __restrict__ cbP,
                                                const float* __restrict__ e2,
                                                int* __restrict__ idx1,
                                                float* __restrict__ outIdxF) {
    const int t = blockIdx.x * 256 + threadIdx.x;
    const int g = blockIdx.y, b = blockIdx.z;
    const float* xp = x + ((size_t)(b * 512 + g * SUBD)) * TLEN + t;

    float r[SUBD];
#pragma unroll
    for (int d = 0; d < SUBD; ++d) r[d] = xp[(size_t)d * TLEN];
    float x2 = 0.f;
#pragma unroll
    for (int d = 0; d < SUBD; ++d) x2 = __builtin_fmaf(r[d], r[d], x2);

    const f8* __restrict__ pg = (const f8*)(cbP + ((size_t)g * NGRPS * SUBD) * 8);
    const f8* __restrict__ e8 = (const f8*)(e2 + g * NCODE);

    float best = 1e30f;
    int bidx = 0;
    for (int grp = 0; grp < NGRPS; ++grp) {
        const f8* __restrict__ pp = pg + (size_t)grp * SUBD;
        float acc[8];
#pragma unroll
        for (int j = 0; j < 8; ++j) acc[j] = 0.f;
#pragma unroll
        for (int d = 0; d < SUBD; ++d) {
            f8 c = pp[d];
#pragma unroll
            for (int j = 0; j < 8; ++j) acc[j] = __builtin_fmaf(r[d], c[j], acc[j]);
        }
        f8 ev = e8[grp];
#pragma unroll
        for (int j = 0; j < 8; ++j) {
            float tv = x2 + ev[j];                              // fl(x2 + e2)
            float dist = __builtin_fmaf(-2.0f, acc[j], tv);     // fl(tv - 2a)
            if (dist < best) { best = dist; bidx = grp * 8 + j; }
        }
    }

    int n = b * TLEN + t;
    idx1[g * NVEC + n] = bidx;
    outIdxF[(size_t)g * NVEC + n] = (float)bidx;
}

// Stage 2: residual update (exact ref expr order) + argmin over cb2 + fused
// output write + both losses.
__global__ __launch_bounds__(256, 4) void k_vq2(const float* __restrict__ x,
                                                const float* __restrict__ cb1,
                                                const float* __restrict__ cb2,
                                                const float* __restrict__ cbP,
                                                const float* __restrict__ e2,
                                                const int* __restrict__ idx1,
                                                float* __restrict__ qout,
                                                float* __restrict__ outIdxF,
                                                double* __restrict__ lossAcc) {
    const int t = blockIdx.x * 256 + threadIdx.x;
    const int g = blockIdx.y, b = blockIdx.z;
    const int n = b * TLEN + t;
    const float* xp = x + ((size_t)(b * 512 + g * SUBD)) * TLEN + t;

    const int i1 = idx1[g * NVEC + n];
    const float* z1p = cb1 + ((size_t)g * NCODE + i1) * SUBD;

    float r[SUBD];
    float x2 = 0.f;
    double ls1 = 0.0;
#pragma unroll
    for (int s = 0; s < 16; ++s) {
        float4 z = ((const float4*)z1p)[s];
#pragma unroll
        for (int dd = 0; dd < 4; ++dd) {
            int d = 4 * s + dd;
            float rv = xp[(size_t)d * TLEN];
            float zz = ((const float*)&z)[dd];
            float tt = zz - rv;               // fl(z - r)      (loss1 term)
            float zst = rv + tt;              // fl(r + tt)
            ls1 += (double)(tt * tt);
            float r2 = rv - zst;              // fl(r - zst) -> residual2
            r[d] = r2;
            x2 = __builtin_fmaf(r2, r2, x2);  // ascending-d chain
        }
    }

    const f8* __restrict__ pg = (const f8*)(cbP + ((size_t)g * NGRPS * SUBD) * 8);
    const f8* __restrict__ e8 = (const f8*)(e2 + g * NCODE);

    float best = 1e30f;
    int bidx = 0;
    for (int grp = 0; grp < NGRPS; ++grp) {
        const f8* __restrict__ pp = pg + (size_t)grp * SUBD;
        float acc[8];
#pragma unroll
        for (int j = 0; j < 8; ++j) acc[j] = 0.f;
#pragma unroll
        for (int d = 0; d < SUBD; ++d) {
            f8 c = pp[d];
#pragma unroll
            for (int j = 0; j < 8; ++j) acc[j] = __builtin_fmaf(r[d], c[j], acc[j]);
        }
        f8 ev = e8[grp];
#pragma unroll
        for (int j = 0; j < 8; ++j) {
            float tv = x2 + ev[j];
            float dist = __builtin_fmaf(-2.0f, acc[j], tv);
            if (dist < best) { best = dist; bidx = grp * 8 + j; }
        }
    }

    outIdxF[(size_t)g * NVEC + n] = (float)bidx;

    // ---- fused output + loss2: q = fl(zst1 + zst2), r[] holds residual2 ----
    const float* z2p = cb2 + ((size_t)g * NCODE + bidx) * SUBD;
    float* op = qout + ((size_t)(b * 512 + g * SUBD)) * TLEN + t;
    double ls2 = 0.0;
#pragma unroll
    for (int s = 0; s < 16; ++s) {
        float4 z1 = ((const float4*)z1p)[s];
        float4 z2 = ((const float4*)z2p)[s];
#pragma unroll
        for (int dd = 0; dd < 4; ++dd) {
            int d = 4 * s + dd;
            float xv = xp[(size_t)d * TLEN];
            float z1v = ((const float*)&z1)[dd];
            float z2v = ((const float*)&z2)[dd];
            float t1 = z1v - xv;
            float zst1 = xv + t1;
            float t2 = z2v - r[d];            // fl(z2 - residual2) (loss2 term)
            float zst2 = r[d] + t2;
            float q = zst1 + zst2;
            op[(size_t)d * TLEN] = q;
            ls2 += (double)(t2 * t2);
        }
    }

    // ---- wave reduce + one atomic per wave for each loss ----
#pragma unroll
    for (int off = 32; off; off >>= 1) {
        ls1 += __shfl_down(ls1, off, 64);
        ls2 += __shfl_down(ls2, off, 64);
    }
    if ((threadIdx.x & 63) == 0) {
        atomicAdd(lossAcc + 0, ls1);
        atomicAdd(lossAcc + 1, ls2);
    }
}

__global__ void k_final(float* __restrict__ lossOut, const double* __restrict__ lossAcc) {
    // loss_i = 1.25 * mean_i ; total = (l1+l2)/2 = 0.625*(m1+m2)
    double m = (lossAcc[0] + lossAcc[1]) / (double)QOUT;
    lossOut[0] = (float)(0.625 * m);
}

extern "C" void kernel_launch(void* const* d_in, const int* in_sizes, int n_in,
                              void* d_out, int out_size, void* d_ws, size_t ws_size,
                              hipStream_t stream) {
    const float* x   = (const float*)d_in[0];
    const float* cb1 = (const float*)d_in[1];
    const float* cb2 = (const float*)d_in[2];
    float* out = (float*)d_out;

    char* ws = (char*)d_ws;
    double* lossAcc = (double*)ws;
    float* e2   = (float*)(ws + WS_E2);
    int*   idx1 = (int*)(ws + WS_IDX1);
    float* cbP1 = (float*)(ws + WS_P1);
    float* cbP2 = (float*)(ws + WS_P2);

    hipMemsetAsync(ws, 0, 16, stream);

    k_e2<<<dim3(64), dim3(256), 0, stream>>>(cb1, cb2, e2);
    k_panel<<<dim3(64), dim3(256), 0, stream>>>(cb1, cb2, cbP1, cbP2);

    dim3 grid(TLEN / 256, GRP, NBATCH);              // (16, 8, 8) = 1024 blocks
    float* outIdx = out + QOUT + 1;
    k_vq1<<<grid, dim3(256), 0, stream>>>(x, cbP1, e2, idx1, outIdx);
    k_vq2<<<grid, dim3(256), 0, stream>>>(x, cb1, cb2, cbP2, e2 + GRP * NCODE,
                                          idx1, out, outIdx + (size_t)GRP * NVEC, lossAcc);
    k_final<<<1, 1, 0, stream>>>(out + QOUT, lossAcc);
}

// Round 5
// 953.457 us; speedup vs baseline: 1.8747x; 1.8747x over previous
//
#include <hip/hip_runtime.h>

#define GRP 8
#define SUBD 64
#define NCODE 1024
#define TLEN 4096
#define NBATCH 8
#define NVEC (NBATCH * TLEN)          // 32768
#define QOUT (NBATCH * 512 * TLEN)    // 16777216
#define ROWS 128                      // x rows per block

// ws layout (bytes):
// [0]        double lossAcc[2]
// [16]       float e2[2*GRP*NCODE]            64 KB
// [65552]    int idx1[GRP*NVEC]               1 MB
// [1114128]  float cbT1[GRP*SUBD*NCODE]       2 MB   [g][d][k]
// [3211280]  float cbT2[GRP*SUBD*NCODE]       2 MB
#define WS_E2   16
#define WS_IDX1 (16 + 65536)
#define WS_CBT1 (WS_IDX1 + 1048576)
#define WS_CBT2 (WS_CBT1 + 2097152)

typedef const __attribute__((address_space(1))) char GCHAR;
typedef __attribute__((address_space(3))) char LCHAR;

__global__ __launch_bounds__(256) void k_e2(const float* __restrict__ cb1,
                                            const float* __restrict__ cb2,
                                            float* __restrict__ e2) {
    int i = blockIdx.x * 256 + threadIdx.x;      // 0 .. 16383
    const float* c = (i < GRP * NCODE) ? (cb1 + (size_t)i * SUBD)
                                       : (cb2 + (size_t)(i - GRP * NCODE) * SUBD);
    float s = 0.f;
#pragma unroll
    for (int d = 0; d < SUBD; ++d) s = __builtin_fmaf(c[d], c[d], s);
    e2[i] = s;
}

// cbT[g][d][k] = cb[g][k][d]
__global__ __launch_bounds__(256) void k_tr(const float* __restrict__ cb1,
                                            const float* __restrict__ cb2,
                                            float* __restrict__ cbT1,
                                            float* __restrict__ cbT2) {
    int i = blockIdx.x * 256 + threadIdx.x;      // 0 .. 16383
    int sel = i >> 13, g = (i >> 10) & 7, k = i & 1023;
    const float* src = (sel ? cb2 : cb1) + ((size_t)g * NCODE + k) * SUBD;
    float* dst = (sel ? cbT2 : cbT1) + (size_t)g * SUBD * NCODE + k;
#pragma unroll
    for (int s = 0; s < 16; ++s) {
        float4 v = ((const float4*)src)[s];
#pragma unroll
        for (int dd = 0; dd < 4; ++dd) dst[(size_t)(4 * s + dd) * NCODE] = ((const float*)&v)[dd];
    }
}

// Block: 256 thr = 4 waves over 128 rows.  Waves 0,1: rows 0-63/64-127, codes
// [0,512).  Waves 2,3: same rows, codes [512,1024).  Lane: ng=lane&7 -> 8 rows
// (n0 = (w&1)*64 + ng*8), kg=lane>>3 -> 8 codes (k = half*512 + c*64 + kg*8 + j).
// Per d: 2 ds_read_b128 (x) + 2 global dwordx4 (cbT) + 128 fma, acc[8][8].
// Exactness: every xe is one ascending-d fma chain; dist = fma(-2,acc,fl(x2+e2));
// per-thread k ascending (strict <); cross-lane/cross-half merges lexicographic
// (dist, then k) == reference first-index argmin.
template <int STAGE2>
__global__ __launch_bounds__(256, 2) void k_vq(
    const float* __restrict__ x,
    const float* __restrict__ cb1,
    const float* __restrict__ cb2,
    const float* __restrict__ cbT,      // transposed codebook to search
    const float* __restrict__ e2,       // e2 row for this codebook (8*1024)
    const int* __restrict__ idxPrev,    // idx1 (stage2)
    int* __restrict__ idxOut,           // idx1 (stage1)
    float* __restrict__ outIdxF,
    float* __restrict__ qout,           // stage2
    double* __restrict__ lossAcc)       // stage2
{
    __shared__ __align__(16) float xs[SUBD * ROWS];   // 32 KB, [d][row]
    __shared__ __align__(16) float e2u[1024];         // e2 slab; later bdH/biH
    __shared__ __align__(16) float x2s[ROWS];
    __shared__ int i1s[ROWS];

    const int tid = threadIdx.x, w = tid >> 6, lane = tid & 63;
    const int g = blockIdx.y, bz = blockIdx.z;
    const int t0 = blockIdx.x * ROWS;

    // ---- stage x tile (d-major, linear dest) + e2 slab via global_load_lds ----
    {
        const float* xsrc = x + ((size_t)(bz * 512 + g * SUBD)) * TLEN + t0;
#pragma unroll
        for (int q = 0; q < 8; ++q) {
            int inst = w * 8 + q;                 // 0..31, 2 d-rows each
            int d = inst * 2 + (lane >> 5);
            const float* gp = xsrc + (size_t)d * TLEN + (lane & 31) * 4;
            float* lp = xs + inst * 256;
            __builtin_amdgcn_global_load_lds((GCHAR*)gp, (LCHAR*)lp, 16, 0, 0);
        }
        const float* ep = e2 + g * NCODE + w * 256 + lane * 4;
        float* lp = e2u + w * 256;
        __builtin_amdgcn_global_load_lds((GCHAR*)ep, (LCHAR*)lp, 16, 0, 0);
    }
    __syncthreads();

    // ---- per-row pass (tid<128): stage2 residual update + loss1; x2 chain ----
    double ls1 = 0.0;
    if (tid < ROWS) {
        float xx = 0.f;
        if (STAGE2) {
            int nv = bz * TLEN + t0 + tid;
            int i1 = idxPrev[g * NVEC + nv];
            i1s[tid] = i1;
            const float4* zr = (const float4*)(cb1 + ((size_t)g * NCODE + i1) * SUBD);
#pragma unroll
            for (int s = 0; s < 16; ++s) {
                float4 z = zr[s];
#pragma unroll
                for (int dd = 0; dd < 4; ++dd) {
                    int d = 4 * s + dd;
                    float r = xs[d * ROWS + tid];
                    float zz = ((const float*)&z)[dd];
                    float tt = zz - r;            // fl(z - r)   (loss1 term)
                    float zst = r + tt;           // fl(r + tt)
                    ls1 += (double)(tt * tt);
                    float r2 = r - zst;           // fl(r - zst) -> residual2
                    xs[d * ROWS + tid] = r2;
                    xx = __builtin_fmaf(r2, r2, xx);   // ascending-d chain
                }
            }
        } else {
#pragma unroll
            for (int d = 0; d < SUBD; ++d) {
                float r = xs[d * ROWS + tid];
                xx = __builtin_fmaf(r, r, xx);
            }
        }
        x2s[tid] = xx;
    }
    __syncthreads();

    // ---- GEMM + argmin ----
    const int ng = lane & 7, kg = lane >> 3;
    const int half = w >> 1;
    const int n0 = (w & 1) * 64 + ng * 8;

    float x2r[8];
    {
        float4 a = *(const float4*)(x2s + n0);
        float4 b = *(const float4*)(x2s + n0 + 4);
#pragma unroll
        for (int i = 0; i < 4; ++i) {
            x2r[i] = ((const float*)&a)[i];
            x2r[i + 4] = ((const float*)&b)[i];
        }
    }

    float best[8];
    int bidx[8];
#pragma unroll
    for (int i = 0; i < 8; ++i) { best[i] = 1e30f; bidx[i] = 0; }

    const float* cbTg = cbT + (size_t)g * SUBD * NCODE;   // [d][1024]

    for (int c = 0; c < 8; ++c) {
        const int kb = half * 512 + c * 64 + kg * 8;
        const float* cp = cbTg + kb;
        float acc[8][8];
#pragma unroll
        for (int i = 0; i < 8; ++i)
#pragma unroll
            for (int j = 0; j < 8; ++j) acc[i][j] = 0.f;

#pragma unroll 2
        for (int d = 0; d < SUBD; ++d) {
            float4 xa = *(const float4*)(xs + d * ROWS + n0);
            float4 xb = *(const float4*)(xs + d * ROWS + n0 + 4);
            float4 c0 = *(const float4*)(cp + (size_t)d * NCODE);
            float4 c1 = *(const float4*)(cp + (size_t)d * NCODE + 4);
#pragma unroll
            for (int i = 0; i < 4; ++i) {
                float xv = ((const float*)&xa)[i];
#pragma unroll
                for (int j = 0; j < 4; ++j) {
                    acc[i][j]     = __builtin_fmaf(xv, ((const float*)&c0)[j], acc[i][j]);
                    acc[i][j + 4] = __builtin_fmaf(xv, ((const float*)&c1)[j], acc[i][j + 4]);
                }
            }
#pragma unroll
            for (int i = 0; i < 4; ++i) {
                float xv = ((const float*)&xb)[i];
#pragma unroll
                for (int j = 0; j < 4; ++j) {
                    acc[i + 4][j]     = __builtin_fmaf(xv, ((const float*)&c0)[j], acc[i + 4][j]);
                    acc[i + 4][j + 4] = __builtin_fmaf(xv, ((const float*)&c1)[j], acc[i + 4][j + 4]);
                }
            }
        }

        float4 e0 = *(const float4*)(e2u + kb);
        float4 e1 = *(const float4*)(e2u + kb + 4);
#pragma unroll
        for (int j = 0; j < 8; ++j) {
            float e2k = (j < 4) ? ((const float*)&e0)[j] : ((const float*)&e1)[j - 4];
            int k = kb + j;
#pragma unroll
            for (int i = 0; i < 8; ++i) {
                float tv = x2r[i] + e2k;                            // fl(x2 + e2)
                float dist = __builtin_fmaf(-2.0f, acc[i][j], tv);  // fl(tv - 2a)
                if (dist < best[i]) { best[i] = dist; bidx[i] = k; }  // ascending k
            }
        }
    }

    // ---- lexicographic reduce across kg lanes (bits 3..5) ----
#pragma unroll
    for (int i = 0; i < 8; ++i) {
        float bd = best[i];
        int bi = bidx[i];
#pragma unroll
        for (int m = 8; m < 64; m <<= 1) {
            float od = __shfl_xor(bd, m, 64);
            int oi = __shfl_xor(bi, m, 64);
            if (od < bd || (od == bd && oi < bi)) { bd = od; bi = oi; }
        }
        best[i] = bd; bidx[i] = bi;
    }

    __syncthreads();                       // all waves done reading e2u
    float* bdH = e2u;                      // [2][128]
    int* biH = (int*)(e2u + 256);          // [2][128]
#pragma unroll
    for (int i = 0; i < 8; ++i) {
        if (i == kg) {                     // static index into best/bidx
            bdH[half * 128 + n0 + i] = best[i];
            biH[half * 128 + n0 + i] = bidx[i];
        }
    }
    __syncthreads();

    // ---- per-row final (tid<128): merge halves, outputs, fused epilogue ----
    double ls2 = 0.0;
    if (tid < ROWS) {
        const int row = tid;
        float dA = bdH[row];
        int iA = biH[row];
        float dB = bdH[128 + row];
        int iB = biH[128 + row];
        int bi = (dB < dA) ? iB : iA;      // tie -> half0 (lower k)
        int n = bz * TLEN + t0 + row;
        outIdxF[(size_t)g * NVEC + n] = (float)bi;
        if (!STAGE2) idxOut[g * NVEC + n] = bi;
        if (STAGE2) {
            const float4* z1v = (const float4*)(cb1 + ((size_t)g * NCODE + i1s[row]) * SUBD);
            const float4* z2v = (const float4*)(cb2 + ((size_t)g * NCODE + bi) * SUBD);
            const float* xp = x + ((size_t)(bz * 512 + g * SUBD)) * TLEN + t0 + row;
            float* op = qout + ((size_t)(bz * 512 + g * SUBD)) * TLEN + t0 + row;
#pragma unroll
            for (int s = 0; s < 16; ++s) {
                float4 z1 = z1v[s];
                float4 z2 = z2v[s];
#pragma unroll
                for (int dd = 0; dd < 4; ++dd) {
                    int d = 4 * s + dd;
                    float xv = xp[(size_t)d * TLEN];
                    float r2 = xs[d * ROWS + row];     // residual2 (bit-exact)
                    float z1f = ((const float*)&z1)[dd];
                    float z2f = ((const float*)&z2)[dd];
                    float t1 = z1f - xv;
                    float zst1 = xv + t1;
                    float t2 = z2f - r2;               // fl(z2 - r2) (loss2)
                    float zst2 = r2 + t2;
                    float q = zst1 + zst2;             // fl(zst1 + zst2)
                    op[(size_t)d * TLEN] = q;
                    ls2 += (double)(t2 * t2);
                }
            }
        }
    }

    if (STAGE2) {
#pragma unroll
        for (int off = 32; off; off >>= 1) {
            ls1 += __shfl_down(ls1, off, 64);
            ls2 += __shfl_down(ls2, off, 64);
        }
        if (w < 2 && lane == 0) {
            atomicAdd(lossAcc + 0, ls1);
            atomicAdd(lossAcc + 1, ls2);
        }
    }
}

__global__ void k_final(float* __restrict__ lossOut, const double* __restrict__ lossAcc) {
    // loss_i = 1.25 * mean_i ; total = (l1+l2)/2 = 0.625*(m1+m2)
    double m = (lossAcc[0] + lossAcc[1]) / (double)QOUT;
    lossOut[0] = (float)(0.625 * m);
}

extern "C" void kernel_launch(void* const* d_in, const int* in_sizes, int n_in,
                              void* d_out, int out_size, void* d_ws, size_t ws_size,
                              hipStream_t stream) {
    const float* x   = (const float*)d_in[0];
    const float* cb1 = (const float*)d_in[1];
    const float* cb2 = (const float*)d_in[2];
    float* out = (float*)d_out;

    char* ws = (char*)d_ws;
    double* lossAcc = (double*)ws;
    float* e2   = (float*)(ws + WS_E2);
    int*   idx1 = (int*)(ws + WS_IDX1);
    float* cbT1 = (float*)(ws + WS_CBT1);
    float* cbT2 = (float*)(ws + WS_CBT2);

    hipMemsetAsync(ws, 0, 16, stream);

    k_e2<<<dim3(64), dim3(256), 0, stream>>>(cb1, cb2, e2);
    k_tr<<<dim3(64), dim3(256), 0, stream>>>(cb1, cb2, cbT1, cbT2);

    dim3 grid(TLEN / ROWS, GRP, NBATCH);                   // (32, 8, 8)
    float* outIdx = out + QOUT + 1;
    k_vq<0><<<grid, dim3(256), 0, stream>>>(x, cb1, cb2, cbT1, e2,
                                            nullptr, idx1, outIdx, nullptr, nullptr);
    k_vq<1><<<grid, dim3(256), 0, stream>>>(x, cb1, cb2, cbT2, e2 + GRP * NCODE,
                                            idx1, nullptr, outIdx + (size_t)GRP * NVEC,
                                            out, lossAcc);
    k_final<<<1, 1, 0, stream>>>(out + QOUT, lossAcc);
}